// Round 1
// baseline (601.739 us; speedup 1.0000x reference)
//
#include <hip/hip_runtime.h>
#include <math.h>

#define E_ 4
#define B_ 128
#define Q_ 900
#define C_ 256
#define H_ 16
#define QC (Q_ * C_)   // 230400

// ---------------------------------------------------------------------------
// Kernel 1: expert_probs[b,e] = sigmoid(mean_q logits[e,b,q,0])
// One wave (64 lanes) per (e,b) pair. Lanes stride over q (stride C floats).
// ---------------------------------------------------------------------------
__global__ void probs_kernel(const float* __restrict__ logits,
                             float* __restrict__ out_probs) {
    int eb = blockIdx.x;          // eb = e*B + b  (matches memory layout)
    int e  = eb / B_;
    int b  = eb % B_;
    const float* base = logits + (size_t)eb * QC;
    int lane = threadIdx.x;       // 0..63

    float s = 0.f;
    for (int q = lane; q < Q_; q += 64)
        s += base[(size_t)q * C_];

    // wave-64 butterfly reduction
    #pragma unroll
    for (int off = 32; off > 0; off >>= 1)
        s += __shfl_down(s, off, 64);

    if (lane == 0) {
        float m = s * (1.0f / (float)Q_);
        out_probs[b * E_ + e] = 1.0f / (1.0f + expf(-m));
    }
}

// ---------------------------------------------------------------------------
// Kernel 2: gating MLP + softmax + top-2 + renormalize. One thread per b.
// ---------------------------------------------------------------------------
__global__ void gate_kernel(const float* __restrict__ probs,   // [B,E]
                            const float* __restrict__ W1,      // [E,H]
                            const float* __restrict__ b1,      // [H]
                            const float* __restrict__ W2,      // [H,E]
                            const float* __restrict__ b2,      // [E]
                            float* __restrict__ out_norm_w,    // [B,E]
                            float* __restrict__ out_final,     // [B]
                            float* __restrict__ out_topidx,    // [B,2] (as float)
                            float* __restrict__ ws_w,          // [2,B]
                            int*   __restrict__ ws_i) {        // [2,B]
    int b = threadIdx.x;
    if (b >= B_) return;

    float p[E_];
    #pragma unroll
    for (int e = 0; e < E_; e++) p[e] = probs[b * E_ + e];

    // h = relu(p @ W1 + b1)
    float h[H_];
    #pragma unroll
    for (int j = 0; j < H_; j++) {
        float a = b1[j];
        #pragma unroll
        for (int e = 0; e < E_; e++) a += p[e] * W1[e * H_ + j];
        h[j] = fmaxf(a, 0.f);
    }

    // logits = h @ W2 + b2 ; softmax
    float lg[E_];
    float mx = -1e30f;
    #pragma unroll
    for (int e = 0; e < E_; e++) {
        float a = b2[e];
        #pragma unroll
        for (int j = 0; j < H_; j++) a += h[j] * W2[j * E_ + e];
        lg[e] = a;
        mx = fmaxf(mx, a);
    }
    float w[E_];
    float sum = 0.f;
    #pragma unroll
    for (int e = 0; e < E_; e++) { w[e] = expf(lg[e] - mx); sum += w[e]; }
    float inv = 1.0f / sum;
    #pragma unroll
    for (int e = 0; e < E_; e++) w[e] *= inv;

    // top-2 (strict > keeps lowest index on ties, matching jax.lax.top_k)
    int i0 = 0;
    #pragma unroll
    for (int e = 1; e < E_; e++) if (w[e] > w[i0]) i0 = e;
    int i1 = -1;
    #pragma unroll
    for (int e = 0; e < E_; e++)
        if (e != i0 && (i1 < 0 || w[e] > w[i1])) i1 = e;

    float s2  = w[i0] + w[i1] + 1e-8f;
    float nw0 = w[i0] / s2;
    float nw1 = w[i1] / s2;

    #pragma unroll
    for (int e = 0; e < E_; e++) out_norm_w[b * E_ + e] = 0.f;
    out_norm_w[b * E_ + i0] = nw0;
    out_norm_w[b * E_ + i1] = nw1;

    out_final[b] = nw0 * p[i0] + nw1 * p[i1];

    out_topidx[b * 2 + 0] = (float)i0;
    out_topidx[b * 2 + 1] = (float)i1;

    ws_w[b]        = nw0;
    ws_w[B_ + b]   = nw1;
    ws_i[b]        = i0;
    ws_i[B_ + b]   = i1;
}

// ---------------------------------------------------------------------------
// Kernel 3: combined[b,q,c] = nw0*logits[i0,b,:,:] + nw1*logits[i1,b,:,:]
// Grid (225, B), block 256. QC/4 = 57600 = 225*256: one float4 per thread.
// ---------------------------------------------------------------------------
__global__ __launch_bounds__(256) void combine_kernel(
        const float* __restrict__ logits,
        const float* __restrict__ ws_w,
        const int*   __restrict__ ws_i,
        float* __restrict__ out) {
    int b  = blockIdx.y;
    float w0 = ws_w[b];
    float w1 = ws_w[B_ + b];
    int   i0 = ws_i[b];
    int   i1 = ws_i[B_ + b];

    const float4* s0 = (const float4*)(logits + (size_t)(i0 * B_ + b) * QC);
    const float4* s1 = (const float4*)(logits + (size_t)(i1 * B_ + b) * QC);
    float4*       o  = (float4*)(out + (size_t)b * QC);

    int idx = blockIdx.x * 256 + threadIdx.x;   // 0..57599
    float4 a = s0[idx];
    float4 c = s1[idx];
    float4 r;
    r.x = w0 * a.x + w1 * c.x;
    r.y = w0 * a.y + w1 * c.y;
    r.z = w0 * a.z + w1 * c.z;
    r.w = w0 * a.w + w1 * c.w;
    o[idx] = r;
}

// ---------------------------------------------------------------------------
extern "C" void kernel_launch(void* const* d_in, const int* in_sizes, int n_in,
                              void* d_out, int out_size, void* d_ws, size_t ws_size,
                              hipStream_t stream) {
    const float* logits = (const float*)d_in[0];  // [E,B,Q,C]
    const float* W1     = (const float*)d_in[1];  // [E,H]
    const float* b1     = (const float*)d_in[2];  // [H]
    const float* W2     = (const float*)d_in[3];  // [H,E]
    const float* b2     = (const float*)d_in[4];  // [E]

    float* out          = (float*)d_out;
    float* out_combined = out;                            // B*Q*C
    float* out_final    = out_combined + (size_t)B_ * QC; // B
    float* out_norm_w   = out_final + B_;                 // B*E
    float* out_probs    = out_norm_w + B_ * E_;           // B*E
    float* out_topidx   = out_probs + B_ * E_;            // B*2

    float* ws_w = (float*)d_ws;           // 2*B floats
    int*   ws_i = (int*)(ws_w + 2 * B_);  // 2*B ints

    probs_kernel<<<E_ * B_, 64, 0, stream>>>(logits, out_probs);
    gate_kernel<<<1, 128, 0, stream>>>(out_probs, W1, b1, W2, b2,
                                       out_norm_w, out_final, out_topidx,
                                       ws_w, ws_i);
    combine_kernel<<<dim3(225, B_), 256, 0, stream>>>(logits, ws_w, ws_i,
                                                      out_combined);
}

// Round 3
// 585.951 us; speedup vs baseline: 1.0269x; 1.0269x over previous
//
#include <hip/hip_runtime.h>
#include <math.h>

#define E_ 4
#define B_ 128
#define Q_ 900
#define C_ 256
#define H_ 16
#define QC (Q_ * C_)   // 230400

typedef float f4_t __attribute__((ext_vector_type(4)));

// ---------------------------------------------------------------------------
// Kernel 1: expert_probs[b,e] = sigmoid(mean_q logits[e,b,q,0])
// One block of 256 threads per (e,b) pair -> 2048 waves (8/CU) for latency
// hiding; each lane issues only ~4 independent strided loads.
// ---------------------------------------------------------------------------
__global__ __launch_bounds__(256) void probs_kernel(
        const float* __restrict__ logits,
        float* __restrict__ out_probs) {
    __shared__ float red[4];
    int eb = blockIdx.x;          // eb = e*B + b  (matches memory layout)
    int e  = eb / B_;
    int b  = eb % B_;
    const float* base = logits + (size_t)eb * QC;
    int t = threadIdx.x;          // 0..255

    float s = 0.f;
    #pragma unroll
    for (int q = t; q < Q_; q += 256)      // q = t, t+256, t+512, t+768
        s += __builtin_nontemporal_load(base + (size_t)q * C_);

    // wave-64 reduction
    #pragma unroll
    for (int off = 32; off > 0; off >>= 1)
        s += __shfl_down(s, off, 64);

    int wave = t >> 6;
    if ((t & 63) == 0) red[wave] = s;
    __syncthreads();
    if (t == 0) {
        float tot = red[0] + red[1] + red[2] + red[3];
        float m = tot * (1.0f / (float)Q_);
        out_probs[b * E_ + e] = 1.0f / (1.0f + expf(-m));
    }
}

// ---------------------------------------------------------------------------
// Kernel 2: gating MLP + softmax + top-2 + renormalize. One thread per b.
// ---------------------------------------------------------------------------
__global__ void gate_kernel(const float* __restrict__ probs,   // [B,E]
                            const float* __restrict__ W1,      // [E,H]
                            const float* __restrict__ b1,      // [H]
                            const float* __restrict__ W2,      // [H,E]
                            const float* __restrict__ b2,      // [E]
                            float* __restrict__ out_norm_w,    // [B,E]
                            float* __restrict__ out_final,     // [B]
                            float* __restrict__ out_topidx,    // [B,2] (as float)
                            float* __restrict__ ws_w,          // [2,B]
                            int*   __restrict__ ws_i) {        // [2,B]
    int b = threadIdx.x;
    if (b >= B_) return;

    float p[E_];
    #pragma unroll
    for (int e = 0; e < E_; e++) p[e] = probs[b * E_ + e];

    // h = relu(p @ W1 + b1)
    float h[H_];
    #pragma unroll
    for (int j = 0; j < H_; j++) {
        float a = b1[j];
        #pragma unroll
        for (int e = 0; e < E_; e++) a += p[e] * W1[e * H_ + j];
        h[j] = fmaxf(a, 0.f);
    }

    // logits = h @ W2 + b2 ; softmax
    float lg[E_];
    float mx = -1e30f;
    #pragma unroll
    for (int e = 0; e < E_; e++) {
        float a = b2[e];
        #pragma unroll
        for (int j = 0; j < H_; j++) a += h[j] * W2[j * E_ + e];
        lg[e] = a;
        mx = fmaxf(mx, a);
    }
    float w[E_];
    float sum = 0.f;
    #pragma unroll
    for (int e = 0; e < E_; e++) { w[e] = expf(lg[e] - mx); sum += w[e]; }
    float inv = 1.0f / sum;
    #pragma unroll
    for (int e = 0; e < E_; e++) w[e] *= inv;

    // top-2 (strict > keeps lowest index on ties, matching jax.lax.top_k)
    int i0 = 0;
    #pragma unroll
    for (int e = 1; e < E_; e++) if (w[e] > w[i0]) i0 = e;
    int i1 = -1;
    #pragma unroll
    for (int e = 0; e < E_; e++)
        if (e != i0 && (i1 < 0 || w[e] > w[i1])) i1 = e;

    float s2  = w[i0] + w[i1] + 1e-8f;
    float nw0 = w[i0] / s2;
    float nw1 = w[i1] / s2;

    #pragma unroll
    for (int e = 0; e < E_; e++) out_norm_w[b * E_ + e] = 0.f;
    out_norm_w[b * E_ + i0] = nw0;
    out_norm_w[b * E_ + i1] = nw1;

    out_final[b] = nw0 * p[i0] + nw1 * p[i1];

    out_topidx[b * 2 + 0] = (float)i0;
    out_topidx[b * 2 + 1] = (float)i1;

    ws_w[b]        = nw0;
    ws_w[B_ + b]   = nw1;
    ws_i[b]        = i0;
    ws_i[B_ + b]   = i1;
}

// ---------------------------------------------------------------------------
// Kernel 3: combined[b,q,c] = nw0*logits[i0,b,:,:] + nw1*logits[i1,b,:,:]
// Grid (225, B), block 256. QC/4 = 57600 = 225*256: one float4 per thread.
// All traffic is touch-once streaming -> nontemporal to skip L2 pollution.
// ---------------------------------------------------------------------------
__global__ __launch_bounds__(256) void combine_kernel(
        const float* __restrict__ logits,
        const float* __restrict__ ws_w,
        const int*   __restrict__ ws_i,
        float* __restrict__ out) {
    int b  = blockIdx.y;
    float w0 = ws_w[b];
    float w1 = ws_w[B_ + b];
    int   i0 = ws_i[b];
    int   i1 = ws_i[B_ + b];

    const f4_t* s0 = (const f4_t*)(logits + (size_t)(i0 * B_ + b) * QC);
    const f4_t* s1 = (const f4_t*)(logits + (size_t)(i1 * B_ + b) * QC);
    f4_t*       o  = (f4_t*)(out + (size_t)b * QC);

    int idx = blockIdx.x * 256 + threadIdx.x;   // 0..57599
    f4_t a = __builtin_nontemporal_load(s0 + idx);
    f4_t c = __builtin_nontemporal_load(s1 + idx);
    f4_t r = w0 * a + w1 * c;
    __builtin_nontemporal_store(r, o + idx);
}

// ---------------------------------------------------------------------------
extern "C" void kernel_launch(void* const* d_in, const int* in_sizes, int n_in,
                              void* d_out, int out_size, void* d_ws, size_t ws_size,
                              hipStream_t stream) {
    const float* logits = (const float*)d_in[0];  // [E,B,Q,C]
    const float* W1     = (const float*)d_in[1];  // [E,H]
    const float* b1     = (const float*)d_in[2];  // [H]
    const float* W2     = (const float*)d_in[3];  // [H,E]
    const float* b2     = (const float*)d_in[4];  // [E]

    float* out          = (float*)d_out;
    float* out_combined = out;                            // B*Q*C
    float* out_final    = out_combined + (size_t)B_ * QC; // B
    float* out_norm_w   = out_final + B_;                 // B*E
    float* out_probs    = out_norm_w + B_ * E_;           // B*E
    float* out_topidx   = out_probs + B_ * E_;            // B*2

    float* ws_w = (float*)d_ws;           // 2*B floats
    int*   ws_i = (int*)(ws_w + 2 * B_);  // 2*B ints

    probs_kernel<<<E_ * B_, 256, 0, stream>>>(logits, out_probs);
    gate_kernel<<<1, 128, 0, stream>>>(out_probs, W1, b1, W2, b2,
                                       out_norm_w, out_final, out_topidx,
                                       ws_w, ws_i);
    combine_kernel<<<dim3(225, B_), 256, 0, stream>>>(logits, ws_w, ws_i,
                                                      out_combined);
}